// Round 1
// baseline (742.817 us; speedup 1.0000x reference)
//
#include <hip/hip_runtime.h>

// GCN encoder: h = relu(agg(x)@W1 + b1); out = agg(h@W2) + b2
// where agg is symmetric-normalized adjacency (with self loops) aggregation.
// Uses identity agg(x@W) == agg(x)@W to pick cheapest order per layer.

constexpr int N  = 100000;   // nodes
constexpr int E  = 1600000;  // edges
constexpr int NB = (N + 255) / 256;  // 391 scan blocks

// ---------------- graph preprocessing ----------------

__global__ void k_count(const int* __restrict__ dst, int* __restrict__ counts) {
  for (int e = blockIdx.x * 256 + threadIdx.x; e < E; e += gridDim.x * 256)
    atomicAdd(&counts[dst[e]], 1);
}

__global__ void k_scan1(const int* __restrict__ counts, int* __restrict__ row_start,
                        int* __restrict__ bs) {
  __shared__ int sm[256];
  int t = threadIdx.x;
  int i = blockIdx.x * 256 + t;
  int v = (i < N) ? counts[i] : 0;
  sm[t] = v;
  __syncthreads();
  #pragma unroll
  for (int s = 1; s < 256; s <<= 1) {
    int u = (t >= s) ? sm[t - s] : 0;
    __syncthreads();
    sm[t] += u;
    __syncthreads();
  }
  if (i < N) row_start[i] = sm[t] - v;       // exclusive within block
  if (t == 255) bs[blockIdx.x] = sm[t];      // block total
}

__global__ void k_scan2(const int* __restrict__ bs, int* __restrict__ bo) {
  __shared__ int sm[512];
  int t = threadIdx.x;
  int v = (t < NB) ? bs[t] : 0;
  sm[t] = v;
  __syncthreads();
  #pragma unroll
  for (int s = 1; s < 512; s <<= 1) {
    int u = (t >= s) ? sm[t - s] : 0;
    __syncthreads();
    sm[t] += u;
    __syncthreads();
  }
  if (t < NB) bo[t] = sm[t] - v;             // exclusive block offsets
}

__global__ void k_finish(int* __restrict__ row_start, const int* __restrict__ bo,
                         const int* __restrict__ counts, float* __restrict__ dinv,
                         int* __restrict__ cursor) {
  int i = blockIdx.x * 256 + threadIdx.x;
  if (i < N) {
    row_start[i] += bo[i >> 8];
    dinv[i] = rsqrtf((float)(counts[i] + 1));  // +1 self loop; deg >= 1 always
    cursor[i] = 0;
  }
}

__global__ void k_fill(const int* __restrict__ src, const int* __restrict__ dst,
                       const int* __restrict__ row_start, int* __restrict__ cursor,
                       int* __restrict__ col) {
  for (int e = blockIdx.x * 256 + threadIdx.x; e < E; e += gridDim.x * 256) {
    int d = dst[e];
    int p = row_start[d] + atomicAdd(&cursor[d], 1);
    col[p] = src[e];
  }
}

// ---------------- normalized aggregation (gather form) ----------------
// out[i][:] = dinv[i] * ( sum_{s in in(i)} dinv[s]*h[s][:] + dinv[i]*h[i][:] ) [+ bias]

template <int DIM, bool BIAS>
__global__ __launch_bounds__(256) void k_agg(
    const float* __restrict__ h, const int* __restrict__ row_start,
    const int* __restrict__ counts, const int* __restrict__ col,
    const float* __restrict__ dinv, const float* __restrict__ bias,
    float* __restrict__ out) {
  constexpr int NPB = 256 / DIM;
  int node = blockIdx.x * NPB + threadIdx.x / DIM;
  int d = threadIdx.x % DIM;
  if (node >= N) return;
  int s0 = row_start[node];
  int cnt = counts[node];
  float di = dinv[node];
  float acc = di * h[(size_t)node * DIM + d];   // self loop (dinv[i]^2 after final mul)
  for (int e = 0; e < cnt; ++e) {
    int s = col[s0 + e];
    acc = fmaf(dinv[s], h[(size_t)s * DIM + d], acc);
  }
  float r = di * acc;
  if (BIAS) r += bias[d];
  out[(size_t)node * DIM + d] = r;
}

// ---------------- f32 GEMM: out[N,OUTC] = A[N,128] @ W[128,OUTC] ----------------
// Block: 256 threads; each thread computes 1 row x 16 cols (4x float4, col
// stride CT so each LDS read instruction spans all 32 banks / broadcasts).
// Safe in-place (A == out): all reads of a block's rows are staged to LDS
// before any epilogue write, and blocks own disjoint rows.

template <int OUTC, bool RELU_BIAS>
__global__ __launch_bounds__(256) void k_gemm(
    const float* __restrict__ A, const float* __restrict__ W,
    const float* __restrict__ bias, float* __restrict__ out) {
  constexpr int CT = OUTC / 16;    // col-thread groups: 8 (OUTC=128) or 4 (OUTC=64)
  constexpr int ROWS = 256 / CT;   // rows per block: 32 or 64
  constexpr int BK = 64;
  __shared__ float ws[BK * OUTC];
  __shared__ float xs[BK][ROWS + 1];   // transposed x tile, +1 pad vs bank conflicts
  const int tid = threadIdx.x;
  const int c = tid % CT;
  const int r = tid / CT;
  const int rowBase = blockIdx.x * ROWS;

  float4 acc0 = {0, 0, 0, 0}, acc1 = {0, 0, 0, 0}, acc2 = {0, 0, 0, 0}, acc3 = {0, 0, 0, 0};

  for (int kk = 0; kk < 128; kk += BK) {
    // stage W chunk [BK x OUTC], coalesced float4
    #pragma unroll
    for (int idx = tid * 4; idx < BK * OUTC; idx += 1024)
      *reinterpret_cast<float4*>(&ws[idx]) =
          *reinterpret_cast<const float4*>(W + kk * OUTC + idx);
    // stage x tile transposed: xs[k][r] = A[rowBase+r][kk+k]
    #pragma unroll
    for (int idx = tid; idx < ROWS * (BK / 4); idx += 256) {
      int rr = idx >> 4;     // / (BK/4)
      int kq = idx & 15;
      int row = rowBase + rr;
      float4 v = {0, 0, 0, 0};
      if (row < N) v = *reinterpret_cast<const float4*>(A + (size_t)row * 128 + kk + kq * 4);
      xs[kq * 4 + 0][rr] = v.x;
      xs[kq * 4 + 1][rr] = v.y;
      xs[kq * 4 + 2][rr] = v.z;
      xs[kq * 4 + 3][rr] = v.w;
    }
    __syncthreads();
    #pragma unroll 8
    for (int k = 0; k < BK; ++k) {
      float xv = xs[k][r];
      float4 w0 = *reinterpret_cast<const float4*>(&ws[k * OUTC + (c) * 4]);
      float4 w1 = *reinterpret_cast<const float4*>(&ws[k * OUTC + (c + CT) * 4]);
      float4 w2 = *reinterpret_cast<const float4*>(&ws[k * OUTC + (c + 2 * CT) * 4]);
      float4 w3 = *reinterpret_cast<const float4*>(&ws[k * OUTC + (c + 3 * CT) * 4]);
      acc0.x = fmaf(xv, w0.x, acc0.x); acc0.y = fmaf(xv, w0.y, acc0.y);
      acc0.z = fmaf(xv, w0.z, acc0.z); acc0.w = fmaf(xv, w0.w, acc0.w);
      acc1.x = fmaf(xv, w1.x, acc1.x); acc1.y = fmaf(xv, w1.y, acc1.y);
      acc1.z = fmaf(xv, w1.z, acc1.z); acc1.w = fmaf(xv, w1.w, acc1.w);
      acc2.x = fmaf(xv, w2.x, acc2.x); acc2.y = fmaf(xv, w2.y, acc2.y);
      acc2.z = fmaf(xv, w2.z, acc2.z); acc2.w = fmaf(xv, w2.w, acc2.w);
      acc3.x = fmaf(xv, w3.x, acc3.x); acc3.y = fmaf(xv, w3.y, acc3.y);
      acc3.z = fmaf(xv, w3.z, acc3.z); acc3.w = fmaf(xv, w3.w, acc3.w);
    }
    __syncthreads();
  }

  int row = rowBase + r;
  if (row < N) {
    float4 a[4] = {acc0, acc1, acc2, acc3};
    #pragma unroll
    for (int i = 0; i < 4; ++i) {
      int c4 = (c + i * CT) * 4;
      float4 v = a[i];
      if (RELU_BIAS) {
        v.x = fmaxf(v.x + bias[c4 + 0], 0.f);
        v.y = fmaxf(v.y + bias[c4 + 1], 0.f);
        v.z = fmaxf(v.z + bias[c4 + 2], 0.f);
        v.w = fmaxf(v.w + bias[c4 + 3], 0.f);
      }
      *reinterpret_cast<float4*>(out + (size_t)row * OUTC + c4) = v;
    }
  }
}

// ---------------- launch ----------------

extern "C" void kernel_launch(void* const* d_in, const int* in_sizes, int n_in,
                              void* d_out, int out_size, void* d_ws, size_t ws_size,
                              hipStream_t stream) {
  const float* x  = (const float*)d_in[0];
  const int*   ei = (const int*)d_in[1];
  const float* W1 = (const float*)d_in[2];
  const float* b1 = (const float*)d_in[3];
  const float* W2 = (const float*)d_in[4];
  const float* b2 = (const float*)d_in[5];
  float* out = (float*)d_out;
  const int* src = ei;        // edge_index[0]
  const int* dst = ei + E;    // edge_index[1]

  char* p = (char*)d_ws;
  auto alloc = [&](size_t bytes) {
    void* q = p;
    p += (bytes + 255) & ~size_t(255);
    return q;
  };
  int*   counts    = (int*)alloc((size_t)N * 4);
  int*   row_start = (int*)alloc((size_t)N * 4);
  int*   cursor    = (int*)alloc((size_t)N * 4);
  int*   col       = (int*)alloc((size_t)E * 4);
  int*   bs        = (int*)alloc((size_t)NB * 4);
  int*   bo        = (int*)alloc((size_t)NB * 4);
  float* dinv      = (float*)alloc((size_t)N * 4);
  float* bufA      = (float*)alloc((size_t)N * 128 * 4);  // agg(x), then relu(agg(x)W1+b1) in place
  float* bufC      = (float*)alloc((size_t)N * 64 * 4);   // h @ W2

  hipMemsetAsync(counts, 0, (size_t)N * 4, stream);
  k_count<<<2048, 256, 0, stream>>>(dst, counts);
  k_scan1<<<NB, 256, 0, stream>>>(counts, row_start, bs);
  k_scan2<<<1, 512, 0, stream>>>(bs, bo);
  k_finish<<<(N + 255) / 256, 256, 0, stream>>>(row_start, bo, counts, dinv, cursor);
  k_fill<<<2048, 256, 0, stream>>>(src, dst, row_start, cursor, col);

  // layer 1: agg(x) -> bufA, then in-place GEMM + bias + relu
  k_agg<128, false><<<N / 2, 256, 0, stream>>>(x, row_start, counts, col, dinv, nullptr, bufA);
  k_gemm<128, true><<<N / 32, 256, 0, stream>>>(bufA, W1, b1, bufA);

  // layer 2: GEMM first (64-wide agg is cheaper), then agg + bias -> out
  k_gemm<64, false><<<(N + 63) / 64, 256, 0, stream>>>(bufA, W2, nullptr, bufC);
  k_agg<64, true><<<N / 4, 256, 0, stream>>>(bufC, row_start, counts, col, dinv, b2, out);
}

// Round 2
// 468.987 us; speedup vs baseline: 1.5839x; 1.5839x over previous
//
#include <hip/hip_runtime.h>

// GCN encoder: h = relu(agg(x)@W1 + b1); out = agg(h@W2) + b2
// agg = symmetric-normalized adjacency (self loops) aggregation.
// Identities used:
//   agg(x@W) == agg(x)@W            (pick cheapest order per layer)
//   dinv-row-scaling commutes with right-multiply: (dinv*h)@W == dinv*(h@W)
//   -> GEMM1 epilogue writes hs = dinv*relu(...), so layer-2 messages arrive
//      pre-scaled and agg2 needs no per-edge dinv gather.

constexpr int N  = 100000;   // nodes
constexpr int E  = 1600000;  // edges
constexpr int NB = (N + 255) / 256;  // 391 scan blocks

// ---------------- graph preprocessing ----------------

__global__ void k_count(const int* __restrict__ dst, int* __restrict__ counts) {
  for (int e = blockIdx.x * 256 + threadIdx.x; e < E; e += gridDim.x * 256)
    atomicAdd(&counts[dst[e]], 1);
}

__global__ void k_scan1(const int* __restrict__ counts, int* __restrict__ row_start,
                        int* __restrict__ bs) {
  __shared__ int sm[256];
  int t = threadIdx.x;
  int i = blockIdx.x * 256 + t;
  int v = (i < N) ? counts[i] : 0;
  sm[t] = v;
  __syncthreads();
  #pragma unroll
  for (int s = 1; s < 256; s <<= 1) {
    int u = (t >= s) ? sm[t - s] : 0;
    __syncthreads();
    sm[t] += u;
    __syncthreads();
  }
  if (i < N) row_start[i] = sm[t] - v;       // exclusive within block
  if (t == 255) bs[blockIdx.x] = sm[t];      // block total
}

__global__ void k_scan2(const int* __restrict__ bs, int* __restrict__ bo) {
  __shared__ int sm[512];
  int t = threadIdx.x;
  int v = (t < NB) ? bs[t] : 0;
  sm[t] = v;
  __syncthreads();
  #pragma unroll
  for (int s = 1; s < 512; s <<= 1) {
    int u = (t >= s) ? sm[t - s] : 0;
    __syncthreads();
    sm[t] += u;
    __syncthreads();
  }
  if (t < NB) bo[t] = sm[t] - v;             // exclusive block offsets
}

__global__ void k_finish(int* __restrict__ row_start, const int* __restrict__ bo,
                         const int* __restrict__ counts, float* __restrict__ dinv,
                         int* __restrict__ cursor) {
  int i = blockIdx.x * 256 + threadIdx.x;
  if (i < N) {
    row_start[i] += bo[i >> 8];
    dinv[i] = rsqrtf((float)(counts[i] + 1));  // +1 self loop; deg >= 1 always
    cursor[i] = 0;
  }
}

__global__ void k_fill(const int* __restrict__ src, const int* __restrict__ dst,
                       const int* __restrict__ row_start, int* __restrict__ cursor,
                       int* __restrict__ col) {
  for (int e = blockIdx.x * 256 + threadIdx.x; e < E; e += gridDim.x * 256) {
    int d = dst[e];
    int p = row_start[d] + atomicAdd(&cursor[d], 1);
    col[p] = src[e];
  }
}

// ---------------- normalized aggregation (gather form) ----------------
// SRC_SCALE=1: out[i] = dinv[i]*( sum_s dinv[s]*h[s] + dinv[i]*h[i] )
// SRC_SCALE=0: out[i] = dinv[i]*( sum_s        h[s] +         h[i] ) [+bias]
//              (h already pre-scaled by dinv upstream)
// float4 lanes (L per node), 4-wide edge unroll with clamped idx + zero wgt
// so every gather iteration has 4 independent loads in flight.

template <int DIM, bool SRC_SCALE, bool BIAS>
__global__ __launch_bounds__(256) void k_agg(
    const float* __restrict__ h, const int* __restrict__ row_start,
    const int* __restrict__ counts, const int* __restrict__ col,
    const float* __restrict__ dinv, const float* __restrict__ bias,
    float* __restrict__ out) {
  constexpr int L = DIM / 4;       // lanes per node (32 or 16)
  constexpr int NPB = 256 / L;     // nodes per block (8 or 16)
  const int node = blockIdx.x * NPB + threadIdx.x / L;
  const int lane = threadIdx.x % L;
  if (node >= N) return;
  const float4* __restrict__ h4 = reinterpret_cast<const float4*>(h);
  const int s0 = row_start[node];
  const int cnt = counts[node];
  const float di = dinv[node];

  float4 a0, a1 = {0,0,0,0}, a2 = {0,0,0,0}, a3 = {0,0,0,0};
  {  // self loop term
    float4 v = h4[(size_t)node * L + lane];
    float w = SRC_SCALE ? di : 1.0f;
    a0.x = w * v.x; a0.y = w * v.y; a0.z = w * v.z; a0.w = w * v.w;
  }
  for (int e = 0; e < cnt; e += 4) {
    int last = cnt - 1;
    int i1 = min(e + 1, last), i2 = min(e + 2, last), i3 = min(e + 3, last);
    int sA = col[s0 + e];
    int sB = col[s0 + i1];
    int sC = col[s0 + i2];
    int sD = col[s0 + i3];
    float wA = SRC_SCALE ? dinv[sA] : 1.0f;
    float wB = (e + 1 <= last) ? (SRC_SCALE ? dinv[sB] : 1.0f) : 0.0f;
    float wC = (e + 2 <= last) ? (SRC_SCALE ? dinv[sC] : 1.0f) : 0.0f;
    float wD = (e + 3 <= last) ? (SRC_SCALE ? dinv[sD] : 1.0f) : 0.0f;
    float4 vA = h4[(size_t)sA * L + lane];
    float4 vB = h4[(size_t)sB * L + lane];
    float4 vC = h4[(size_t)sC * L + lane];
    float4 vD = h4[(size_t)sD * L + lane];
    a0.x = fmaf(wA, vA.x, a0.x); a0.y = fmaf(wA, vA.y, a0.y);
    a0.z = fmaf(wA, vA.z, a0.z); a0.w = fmaf(wA, vA.w, a0.w);
    a1.x = fmaf(wB, vB.x, a1.x); a1.y = fmaf(wB, vB.y, a1.y);
    a1.z = fmaf(wB, vB.z, a1.z); a1.w = fmaf(wB, vB.w, a1.w);
    a2.x = fmaf(wC, vC.x, a2.x); a2.y = fmaf(wC, vC.y, a2.y);
    a2.z = fmaf(wC, vC.z, a2.z); a2.w = fmaf(wC, vC.w, a2.w);
    a3.x = fmaf(wD, vD.x, a3.x); a3.y = fmaf(wD, vD.y, a3.y);
    a3.z = fmaf(wD, vD.z, a3.z); a3.w = fmaf(wD, vD.w, a3.w);
  }
  float4 r;
  r.x = di * ((a0.x + a1.x) + (a2.x + a3.x));
  r.y = di * ((a0.y + a1.y) + (a2.y + a3.y));
  r.z = di * ((a0.z + a1.z) + (a2.z + a3.z));
  r.w = di * ((a0.w + a1.w) + (a2.w + a3.w));
  if (BIAS) {
    const float4 b = reinterpret_cast<const float4*>(bias)[lane];
    r.x += b.x; r.y += b.y; r.z += b.z; r.w += b.w;
  }
  reinterpret_cast<float4*>(out)[(size_t)node * L + lane] = r;
}

// ---------------- f32 GEMM: out[N,OUTC] = A[N,128] @ W[128,OUTC] ----------------
// RELU_BIAS epilogue optionally also scales rows by dscale[row] (for the
// layer-2 pre-scaling identity). Safe in-place (A == out): all reads of a
// block's rows are staged to LDS before the epilogue writes.

template <int OUTC, bool RELU_BIAS, bool OUT_SCALE>
__global__ __launch_bounds__(256) void k_gemm(
    const float* __restrict__ A, const float* __restrict__ W,
    const float* __restrict__ bias, const float* __restrict__ dscale,
    float* __restrict__ out) {
  constexpr int CT = OUTC / 16;    // col-thread groups: 8 (OUTC=128) or 4 (OUTC=64)
  constexpr int ROWS = 256 / CT;   // rows per block: 32 or 64
  constexpr int BK = 64;
  __shared__ float ws[BK * OUTC];
  __shared__ float xs[BK][ROWS + 1];
  const int tid = threadIdx.x;
  const int c = tid % CT;
  const int r = tid / CT;
  const int rowBase = blockIdx.x * ROWS;

  float4 acc0 = {0, 0, 0, 0}, acc1 = {0, 0, 0, 0}, acc2 = {0, 0, 0, 0}, acc3 = {0, 0, 0, 0};

  for (int kk = 0; kk < 128; kk += BK) {
    #pragma unroll
    for (int idx = tid * 4; idx < BK * OUTC; idx += 1024)
      *reinterpret_cast<float4*>(&ws[idx]) =
          *reinterpret_cast<const float4*>(W + kk * OUTC + idx);
    #pragma unroll
    for (int idx = tid; idx < ROWS * (BK / 4); idx += 256) {
      int rr = idx >> 4;
      int kq = idx & 15;
      int row = rowBase + rr;
      float4 v = {0, 0, 0, 0};
      if (row < N) v = *reinterpret_cast<const float4*>(A + (size_t)row * 128 + kk + kq * 4);
      xs[kq * 4 + 0][rr] = v.x;
      xs[kq * 4 + 1][rr] = v.y;
      xs[kq * 4 + 2][rr] = v.z;
      xs[kq * 4 + 3][rr] = v.w;
    }
    __syncthreads();
    #pragma unroll 8
    for (int k = 0; k < BK; ++k) {
      float xv = xs[k][r];
      float4 w0 = *reinterpret_cast<const float4*>(&ws[k * OUTC + (c) * 4]);
      float4 w1 = *reinterpret_cast<const float4*>(&ws[k * OUTC + (c + CT) * 4]);
      float4 w2 = *reinterpret_cast<const float4*>(&ws[k * OUTC + (c + 2 * CT) * 4]);
      float4 w3 = *reinterpret_cast<const float4*>(&ws[k * OUTC + (c + 3 * CT) * 4]);
      acc0.x = fmaf(xv, w0.x, acc0.x); acc0.y = fmaf(xv, w0.y, acc0.y);
      acc0.z = fmaf(xv, w0.z, acc0.z); acc0.w = fmaf(xv, w0.w, acc0.w);
      acc1.x = fmaf(xv, w1.x, acc1.x); acc1.y = fmaf(xv, w1.y, acc1.y);
      acc1.z = fmaf(xv, w1.z, acc1.z); acc1.w = fmaf(xv, w1.w, acc1.w);
      acc2.x = fmaf(xv, w2.x, acc2.x); acc2.y = fmaf(xv, w2.y, acc2.y);
      acc2.z = fmaf(xv, w2.z, acc2.z); acc2.w = fmaf(xv, w2.w, acc2.w);
      acc3.x = fmaf(xv, w3.x, acc3.x); acc3.y = fmaf(xv, w3.y, acc3.y);
      acc3.z = fmaf(xv, w3.z, acc3.z); acc3.w = fmaf(xv, w3.w, acc3.w);
    }
    __syncthreads();
  }

  int row = rowBase + r;
  if (row < N) {
    float sc = OUT_SCALE ? dscale[row] : 1.0f;
    float4 a[4] = {acc0, acc1, acc2, acc3};
    #pragma unroll
    for (int i = 0; i < 4; ++i) {
      int c4 = (c + i * CT) * 4;
      float4 v = a[i];
      if (RELU_BIAS) {
        v.x = fmaxf(v.x + bias[c4 + 0], 0.f);
        v.y = fmaxf(v.y + bias[c4 + 1], 0.f);
        v.z = fmaxf(v.z + bias[c4 + 2], 0.f);
        v.w = fmaxf(v.w + bias[c4 + 3], 0.f);
      }
      if (OUT_SCALE) {
        v.x *= sc; v.y *= sc; v.z *= sc; v.w *= sc;
      }
      *reinterpret_cast<float4*>(out + (size_t)row * OUTC + c4) = v;
    }
  }
}

// ---------------- launch ----------------

extern "C" void kernel_launch(void* const* d_in, const int* in_sizes, int n_in,
                              void* d_out, int out_size, void* d_ws, size_t ws_size,
                              hipStream_t stream) {
  const float* x  = (const float*)d_in[0];
  const int*   ei = (const int*)d_in[1];
  const float* W1 = (const float*)d_in[2];
  const float* b1 = (const float*)d_in[3];
  const float* W2 = (const float*)d_in[4];
  const float* b2 = (const float*)d_in[5];
  float* out = (float*)d_out;
  const int* src = ei;        // edge_index[0]
  const int* dst = ei + E;    // edge_index[1]

  char* p = (char*)d_ws;
  auto alloc = [&](size_t bytes) {
    void* q = p;
    p += (bytes + 255) & ~size_t(255);
    return q;
  };
  int*   counts    = (int*)alloc((size_t)N * 4);
  int*   row_start = (int*)alloc((size_t)N * 4);
  int*   cursor    = (int*)alloc((size_t)N * 4);
  int*   col       = (int*)alloc((size_t)E * 4);
  int*   bs        = (int*)alloc((size_t)NB * 4);
  int*   bo        = (int*)alloc((size_t)NB * 4);
  float* dinv      = (float*)alloc((size_t)N * 4);
  float* bufA      = (float*)alloc((size_t)N * 128 * 4);  // agg(x) -> hs (in place)
  float* bufC      = (float*)alloc((size_t)N * 64 * 4);   // hs @ W2 (pre-scaled msgs)

  hipMemsetAsync(counts, 0, (size_t)N * 4, stream);
  k_count<<<2048, 256, 0, stream>>>(dst, counts);
  k_scan1<<<NB, 256, 0, stream>>>(counts, row_start, bs);
  k_scan2<<<1, 512, 0, stream>>>(bs, bo);
  k_finish<<<(N + 255) / 256, 256, 0, stream>>>(row_start, bo, counts, dinv, cursor);
  k_fill<<<2048, 256, 0, stream>>>(src, dst, row_start, cursor, col);

  // layer 1: agg(x) -> bufA; in-place GEMM + bias + relu, epilogue *dinv -> hs
  k_agg<128, true, false><<<N / 8, 256, 0, stream>>>(
      x, row_start, counts, col, dinv, nullptr, bufA);
  k_gemm<128, true, true><<<N / 32, 256, 0, stream>>>(bufA, W1, b1, dinv, bufA);

  // layer 2: GEMM (messages arrive pre-scaled), then pure gather-sum + bias
  k_gemm<64, false, false><<<(N + 63) / 64, 256, 0, stream>>>(bufA, W2, nullptr, nullptr, bufC);
  k_agg<64, false, true><<<N / 16, 256, 0, stream>>>(
      bufC, row_start, counts, col, dinv, b2, out);
}

// Round 4
// 443.145 us; speedup vs baseline: 1.6762x; 1.0583x over previous
//
#include <hip/hip_runtime.h>

// GCN encoder: h = relu(agg(x)@W1 + b1); out = agg(h@W2) + b2
// agg = symmetric-normalized adjacency (self loops) aggregation.
// Identities used:
//   agg(x@W) == agg(x)@W                       (pick cheapest order per layer)
//   (dinv*h)@W == dinv*(h@W)                   (pre-scale rows, kill per-edge dinv gather)
// Layer 1 gathers a PRESCALED BF16 copy of x (halves the gather-path bytes,
// which round-2 counters showed is a ~3.3 TB/s structural BW limit).

constexpr int N  = 100000;   // nodes
constexpr int E  = 1600000;  // edges
constexpr int NB = (N + 255) / 256;  // 391 scan blocks

// ---------------- graph preprocessing ----------------

__global__ void k_count(const int* __restrict__ dst, int* __restrict__ counts) {
  for (int e = blockIdx.x * 256 + threadIdx.x; e < E; e += gridDim.x * 256)
    atomicAdd(&counts[dst[e]], 1);
}

__global__ void k_scan1(const int* __restrict__ counts, int* __restrict__ row_start,
                        int* __restrict__ bs) {
  __shared__ int sm[256];
  int t = threadIdx.x;
  int i = blockIdx.x * 256 + t;
  int v = (i < N) ? counts[i] : 0;
  sm[t] = v;
  __syncthreads();
  #pragma unroll
  for (int s = 1; s < 256; s <<= 1) {
    int u = (t >= s) ? sm[t - s] : 0;
    __syncthreads();
    sm[t] += u;
    __syncthreads();
  }
  if (i < N) row_start[i] = sm[t] - v;
  if (t == 255) bs[blockIdx.x] = sm[t];
}

__global__ void k_scan2(const int* __restrict__ bs, int* __restrict__ bo) {
  __shared__ int sm[512];
  int t = threadIdx.x;
  int v = (t < NB) ? bs[t] : 0;
  sm[t] = v;
  __syncthreads();
  #pragma unroll
  for (int s = 1; s < 512; s <<= 1) {
    int u = (t >= s) ? sm[t - s] : 0;
    __syncthreads();
    sm[t] += u;
    __syncthreads();
  }
  if (t < NB) bo[t] = sm[t] - v;
}

__global__ void k_finish(int* __restrict__ row_start, const int* __restrict__ bo,
                         const int* __restrict__ counts, float* __restrict__ dinv,
                         int* __restrict__ cursor) {
  int i = blockIdx.x * 256 + threadIdx.x;
  if (i < N) {
    row_start[i] += bo[i >> 8];
    dinv[i] = rsqrtf((float)(counts[i] + 1));  // +1 self loop
    cursor[i] = 0;
  }
}

__global__ void k_fill(const int* __restrict__ src, const int* __restrict__ dst,
                       const int* __restrict__ row_start, int* __restrict__ cursor,
                       int* __restrict__ col) {
  for (int e = blockIdx.x * 256 + threadIdx.x; e < E; e += gridDim.x * 256) {
    int d = dst[e];
    int p = row_start[d] + atomicAdd(&cursor[d], 1);
    col[p] = src[e];
  }
}

// ---------------- prescaled bf16 copy of x ----------------
// xb[i][d] = bf16_rne(dinv[i] * x[i][d]); one thread -> 8 floats -> uint4.

__device__ __forceinline__ unsigned bf16rne(float f) {
  unsigned u = __float_as_uint(f);
  return (u + 0x7fffu + ((u >> 16) & 1u)) >> 16;
}
__device__ __forceinline__ unsigned pk(float lo, float hi) {
  return bf16rne(lo) | (bf16rne(hi) << 16);
}

__global__ __launch_bounds__(256) void k_tobf16(
    const float* __restrict__ x, const float* __restrict__ dinv,
    uint4* __restrict__ xb) {
  int i = blockIdx.x * 256 + threadIdx.x;   // one uint4 (8 bf16) per thread
  if (i >= N * 16) return;
  float d = dinv[i >> 4];
  const float4* x4 = reinterpret_cast<const float4*>(x);
  float4 v0 = x4[(size_t)i * 2];
  float4 v1 = x4[(size_t)i * 2 + 1];
  uint4 o;
  o.x = pk(d * v0.x, d * v0.y);
  o.y = pk(d * v0.z, d * v0.w);
  o.z = pk(d * v1.x, d * v1.y);
  o.w = pk(d * v1.z, d * v1.w);
  xb[i] = o;
}

// ---------------- layer-1 aggregation: bf16 gather, f32 accumulate ----------
// out[i] = dinv[i] * ( sum_{s in in(i)} xb[s] + xb[i] )   (xb prescaled by dinv)
// 16 lanes/node, each lane owns 8 dims (one uint4 = 8 bf16). 4-wide edge
// unroll with clamped idx + 0/1 weight keeps 4 gathers in flight.

__device__ __forceinline__ void acc8(float (&a)[8], const uint4& u, float wgt) {
  a[0] = fmaf(wgt, __uint_as_float(u.x << 16), a[0]);
  a[1] = fmaf(wgt, __uint_as_float(u.x & 0xffff0000u), a[1]);
  a[2] = fmaf(wgt, __uint_as_float(u.y << 16), a[2]);
  a[3] = fmaf(wgt, __uint_as_float(u.y & 0xffff0000u), a[3]);
  a[4] = fmaf(wgt, __uint_as_float(u.z << 16), a[4]);
  a[5] = fmaf(wgt, __uint_as_float(u.z & 0xffff0000u), a[5]);
  a[6] = fmaf(wgt, __uint_as_float(u.w << 16), a[6]);
  a[7] = fmaf(wgt, __uint_as_float(u.w & 0xffff0000u), a[7]);
}

__global__ __launch_bounds__(256) void k_agg1(
    const uint4* __restrict__ xb, const int* __restrict__ row_start,
    const int* __restrict__ counts, const int* __restrict__ col,
    const float* __restrict__ dinv, float* __restrict__ out) {
  const int node = blockIdx.x * 16 + (threadIdx.x >> 4);
  const int lane = threadIdx.x & 15;
  if (node >= N) return;
  const int s0 = row_start[node];
  const int cnt = counts[node];
  const float di = dinv[node];

  float a[8] = {0, 0, 0, 0, 0, 0, 0, 0};
  acc8(a, xb[(size_t)node * 16 + lane], 1.0f);  // self loop
  for (int e = 0; e < cnt; e += 4) {
    const int last = cnt - 1;
    int sA = col[s0 + e];
    int sB = col[s0 + min(e + 1, last)];
    int sC = col[s0 + min(e + 2, last)];
    int sD = col[s0 + min(e + 3, last)];
    float wB = (e + 1 <= last) ? 1.0f : 0.0f;
    float wC = (e + 2 <= last) ? 1.0f : 0.0f;
    float wD = (e + 3 <= last) ? 1.0f : 0.0f;
    uint4 vA = xb[(size_t)sA * 16 + lane];
    uint4 vB = xb[(size_t)sB * 16 + lane];
    uint4 vC = xb[(size_t)sC * 16 + lane];
    uint4 vD = xb[(size_t)sD * 16 + lane];
    acc8(a, vA, 1.0f);
    acc8(a, vB, wB);
    acc8(a, vC, wC);
    acc8(a, vD, wD);
  }
  float4 r0 = {di * a[0], di * a[1], di * a[2], di * a[3]};
  float4 r1 = {di * a[4], di * a[5], di * a[6], di * a[7]};
  float4* o4 = reinterpret_cast<float4*>(out) + (size_t)node * 32 + lane * 2;
  o4[0] = r0;
  o4[1] = r1;
}

// ---------------- layer-2 aggregation: f32 gather (prescaled msgs) ---------
// out[i] = dinv[i] * ( sum_s h[s] + h[i] ) + bias

__global__ __launch_bounds__(256) void k_agg2(
    const float* __restrict__ h, const int* __restrict__ row_start,
    const int* __restrict__ counts, const int* __restrict__ col,
    const float* __restrict__ dinv, const float* __restrict__ bias,
    float* __restrict__ out) {
  constexpr int L = 16;            // lanes per node (64 dims / 4)
  const int node = blockIdx.x * 16 + threadIdx.x / L;
  const int lane = threadIdx.x % L;
  if (node >= N) return;
  const float4* __restrict__ h4 = reinterpret_cast<const float4*>(h);
  const int s0 = row_start[node];
  const int cnt = counts[node];
  const float di = dinv[node];

  float4 a0 = h4[(size_t)node * L + lane];  // self loop (prescaled)
  float4 a1 = {0,0,0,0}, a2 = {0,0,0,0}, a3 = {0,0,0,0};
  for (int e = 0; e < cnt; e += 4) {
    int last = cnt - 1;
    int sA = col[s0 + e];
    int sB = col[s0 + min(e + 1, last)];
    int sC = col[s0 + min(e + 2, last)];
    int sD = col[s0 + min(e + 3, last)];
    float wB = (e + 1 <= last) ? 1.0f : 0.0f;
    float wC = (e + 2 <= last) ? 1.0f : 0.0f;
    float wD = (e + 3 <= last) ? 1.0f : 0.0f;
    float4 vA = h4[(size_t)sA * L + lane];
    float4 vB = h4[(size_t)sB * L + lane];
    float4 vC = h4[(size_t)sC * L + lane];
    float4 vD = h4[(size_t)sD * L + lane];
    a0.x += vA.x; a0.y += vA.y; a0.z += vA.z; a0.w += vA.w;
    a1.x = fmaf(wB, vB.x, a1.x); a1.y = fmaf(wB, vB.y, a1.y);
    a1.z = fmaf(wB, vB.z, a1.z); a1.w = fmaf(wB, vB.w, a1.w);
    a2.x = fmaf(wC, vC.x, a2.x); a2.y = fmaf(wC, vC.y, a2.y);
    a2.z = fmaf(wC, vC.z, a2.z); a2.w = fmaf(wC, vC.w, a2.w);
    a3.x = fmaf(wD, vD.x, a3.x); a3.y = fmaf(wD, vD.y, a3.y);
    a3.z = fmaf(wD, vD.z, a3.z); a3.w = fmaf(wD, vD.w, a3.w);
  }
  const float4 b = reinterpret_cast<const float4*>(bias)[lane];
  float4 r;
  r.x = fmaf(di, (a0.x + a1.x) + (a2.x + a3.x), b.x);
  r.y = fmaf(di, (a0.y + a1.y) + (a2.y + a3.y), b.y);
  r.z = fmaf(di, (a0.z + a1.z) + (a2.z + a3.z), b.z);
  r.w = fmaf(di, (a0.w + a1.w) + (a2.w + a3.w), b.w);
  reinterpret_cast<float4*>(out)[(size_t)node * L + lane] = r;
}

// ---------------- f32 GEMM: out[N,OUTC] = A[N,128] @ W[128,OUTC] ----------------
// 256 threads; each thread computes 4 rows x 16 cols (LDS ws read amortized
// over 64 FMAs -> FMA-bound, not LDS-bound). Safe in-place (A == out): all
// reads of the block's rows complete (staged per-BK-chunk) before epilogue
// writes, and blocks own disjoint rows.

template <int OUTC, bool RELU_BIAS, bool OUT_SCALE>
__global__ __launch_bounds__(256) void k_gemm(
    const float* __restrict__ A, const float* __restrict__ W,
    const float* __restrict__ bias, const float* __restrict__ dscale,
    float* __restrict__ out) {
  constexpr int CT = OUTC / 16;      // col-groups: 8 (OUTC=128) or 4 (OUTC=64)
  constexpr int TR = 256 / CT;       // thread-rows: 32 or 64
  constexpr int ROWS = TR * 4;       // rows per block: 128 or 256
  constexpr int BK = 32;
  __shared__ float ws[BK * OUTC];
  __shared__ float xs[BK][ROWS + 4];   // +4 keeps float4 alignment of each k-row
  const int tid = threadIdx.x;
  const int c = tid % CT;
  const int r = tid / CT;
  const int rowBase = blockIdx.x * ROWS;

  float4 acc[4][4];
  #pragma unroll
  for (int j = 0; j < 4; ++j)
    #pragma unroll
    for (int i = 0; i < 4; ++i) acc[j][i] = {0, 0, 0, 0};

  for (int kk = 0; kk < 128; kk += BK) {
    #pragma unroll
    for (int idx = tid * 4; idx < BK * OUTC; idx += 1024)
      *reinterpret_cast<float4*>(&ws[idx]) =
          *reinterpret_cast<const float4*>(W + (size_t)kk * OUTC + idx);
    #pragma unroll
    for (int idx = tid; idx < ROWS * (BK / 4); idx += 256) {
      int rr = idx / (BK / 4);
      int kq = idx % (BK / 4);
      int row = rowBase + rr;
      float4 v = {0, 0, 0, 0};
      if (row < N) v = *reinterpret_cast<const float4*>(A + (size_t)row * 128 + kk + kq * 4);
      xs[kq * 4 + 0][rr] = v.x;
      xs[kq * 4 + 1][rr] = v.y;
      xs[kq * 4 + 2][rr] = v.z;
      xs[kq * 4 + 3][rr] = v.w;
    }
    __syncthreads();
    #pragma unroll
    for (int k = 0; k < BK; ++k) {
      float4 xv = *reinterpret_cast<const float4*>(&xs[k][4 * r]);
      #pragma unroll
      for (int i = 0; i < 4; ++i) {
        float4 w = *reinterpret_cast<const float4*>(&ws[k * OUTC + (c + i * CT) * 4]);
        acc[0][i].x = fmaf(xv.x, w.x, acc[0][i].x); acc[0][i].y = fmaf(xv.x, w.y, acc[0][i].y);
        acc[0][i].z = fmaf(xv.x, w.z, acc[0][i].z); acc[0][i].w = fmaf(xv.x, w.w, acc[0][i].w);
        acc[1][i].x = fmaf(xv.y, w.x, acc[1][i].x); acc[1][i].y = fmaf(xv.y, w.y, acc[1][i].y);
        acc[1][i].z = fmaf(xv.y, w.z, acc[1][i].z); acc[1][i].w = fmaf(xv.y, w.w, acc[1][i].w);
        acc[2][i].x = fmaf(xv.z, w.x, acc[2][i].x); acc[2][i].y = fmaf(xv.z, w.y, acc[2][i].y);
        acc[2][i].z = fmaf(xv.z, w.z, acc[2][i].z); acc[2][i].w = fmaf(xv.z, w.w, acc[2][i].w);
        acc[3][i].x = fmaf(xv.w, w.x, acc[3][i].x); acc[3][i].y = fmaf(xv.w, w.y, acc[3][i].y);
        acc[3][i].z = fmaf(xv.w, w.z, acc[3][i].z); acc[3][i].w = fmaf(xv.w, w.w, acc[3][i].w);
      }
    }
    __syncthreads();
  }

  #pragma unroll
  for (int j = 0; j < 4; ++j) {
    int row = rowBase + 4 * r + j;
    if (row < N) {
      float sc = OUT_SCALE ? dscale[row] : 1.0f;
      #pragma unroll
      for (int i = 0; i < 4; ++i) {
        int c4 = (c + i * CT) * 4;
        float4 v = acc[j][i];
        if (RELU_BIAS) {
          v.x = fmaxf(v.x + bias[c4 + 0], 0.f);
          v.y = fmaxf(v.y + bias[c4 + 1], 0.f);
          v.z = fmaxf(v.z + bias[c4 + 2], 0.f);
          v.w = fmaxf(v.w + bias[c4 + 3], 0.f);
        }
        if (OUT_SCALE) { v.x *= sc; v.y *= sc; v.z *= sc; v.w *= sc; }
        *reinterpret_cast<float4*>(out + (size_t)row * OUTC + c4) = v;
      }
    }
  }
}

// ---------------- launch ----------------

extern "C" void kernel_launch(void* const* d_in, const int* in_sizes, int n_in,
                              void* d_out, int out_size, void* d_ws, size_t ws_size,
                              hipStream_t stream) {
  const float* x  = (const float*)d_in[0];
  const int*   ei = (const int*)d_in[1];
  const float* W1 = (const float*)d_in[2];
  const float* b1 = (const float*)d_in[3];
  const float* W2 = (const float*)d_in[4];
  const float* b2 = (const float*)d_in[5];
  float* out = (float*)d_out;
  const int* src = ei;
  const int* dst = ei + E;

  char* p = (char*)d_ws;
  auto alloc = [&](size_t bytes) {
    void* q = p;
    p += (bytes + 255) & ~size_t(255);
    return q;
  };
  int*   counts    = (int*)alloc((size_t)N * 4);
  int*   row_start = (int*)alloc((size_t)N * 4);
  int*   cursor    = (int*)alloc((size_t)N * 4);
  int*   col       = (int*)alloc((size_t)E * 4);
  int*   bs        = (int*)alloc((size_t)NB * 4);
  int*   bo        = (int*)alloc((size_t)NB * 4);
  float* dinv      = (float*)alloc((size_t)N * 4);
  float* bufA      = (float*)alloc((size_t)N * 128 * 4);  // agg1 out -> hs (in place)
  float* bufC      = (float*)alloc((size_t)N * 64 * 4);   // ALIASED: xb (layer1), then hs@W2
  uint4* xb        = (uint4*)bufC;  // bf16 prescaled x: N*256 B == N*64*4 B, dead before gemm2

  (void)hipMemsetAsync(counts, 0, (size_t)N * 4, stream);
  k_count<<<2048, 256, 0, stream>>>(dst, counts);
  k_scan1<<<NB, 256, 0, stream>>>(counts, row_start, bs);
  k_scan2<<<1, 512, 0, stream>>>(bs, bo);
  k_finish<<<(N + 255) / 256, 256, 0, stream>>>(row_start, bo, counts, dinv, cursor);
  k_fill<<<2048, 256, 0, stream>>>(src, dst, row_start, cursor, col);

  // layer 1
  k_tobf16<<<(N * 16 + 255) / 256, 256, 0, stream>>>(x, dinv, xb);
  k_agg1<<<(N + 15) / 16, 256, 0, stream>>>(xb, row_start, counts, col, dinv, bufA);
  k_gemm<128, true, true><<<(N + 127) / 128, 256, 0, stream>>>(bufA, W1, b1, dinv, bufA);

  // layer 2 (xb dead; bufC reused as GEMM2 output)
  k_gemm<64, false, false><<<(N + 255) / 256, 256, 0, stream>>>(bufA, W2, nullptr, nullptr, bufC);
  k_agg2<<<(N + 15) / 16, 256, 0, stream>>>(bufC, row_start, counts, col, dinv, b2, out);
}